// Round 18
// baseline (319.864 us; speedup 1.0000x reference)
//
#include <hip/hip_runtime.h>
#include <hip/hip_fp16.h>
#include <math.h>

// Mesh encoder: 4x (spiral conv + ELU + sparse pool) + final GEMM.
// VERTS = [65536, 16384, 4096, 1024, 256], SEQ=9, CH=[3,32,64,128,256], B=16.
//
// R12: vertex-major; wave = ES edges x 16 batches; A=W^T, B=x; sorted edges.
// R15: channel-tiled layout XB[v][c/8][b][c%8], 16B B-fragment loads.
// R17: fp16 activations + inline-asm global_atomic_pk_add_f16 direct pooling.
// R18: MLP push — L0 hoists all 16 gathers into registers before compute;
// L1-L3 u-loop unrolled x3 so 3 k-steps' gathers batch-issue (conv levels
// are HBM-latency-bound on random gather misses, ~2 outstanding/wave);
// memsets consolidated upfront (x1b|x2b|x3b contiguous single memset).

#define SEQL 9

typedef __attribute__((ext_vector_type(8))) _Float16 f16x8;
typedef __attribute__((ext_vector_type(4))) _Float16 f16x4;
typedef __attribute__((ext_vector_type(4))) float f32x4;

__device__ __forceinline__ void atomic_pk_f16(unsigned short* addr, float a, float b) {
    const unsigned v =
        (unsigned)__builtin_bit_cast(unsigned short, (_Float16)a) |
        ((unsigned)__builtin_bit_cast(unsigned short, (_Float16)b) << 16);
    asm volatile("global_atomic_pk_add_f16 %0, %1, off"
                 :: "v"(addr), "v"(v) : "memory");
}

// ---------- prep ----------

// W [9*CIN][COUT] fp32 -> WTh/WTl [K/32][COUT][32] fp16 hi/lo (zero-padded).
template<int CIN, int CINP, int COUT, int K>
__global__ __launch_bounds__(256)
void wt_prep(const float* __restrict__ W, unsigned short* __restrict__ WTh,
             unsigned short* __restrict__ WTl)
{
    const int t = blockIdx.x * 256 + threadIdx.x;
    if (t >= COUT * K) return;
    const int u = t / (COUT * 32);
    const int rem = t % (COUT * 32);
    const int co = rem / 32, kk = rem % 32;
    const int k = u * 32 + kk;
    const int s = k / CINP, c = k % CINP;
    float w = (s < 9 && c < CIN) ? W[(size_t)(s * CIN + c) * COUT + co] : 0.0f;
    _Float16 h = (_Float16)w;
    _Float16 l = (_Float16)(w - (float)h);
    WTh[t] = __builtin_bit_cast(unsigned short, h);
    WTl[t] = __builtin_bit_cast(unsigned short, l);
}

// x [16][65536][3] -> XB0 fp16 [65536][16][4] (c=3 zero pad)
__global__ __launch_bounds__(256)
void build_x0T(const float* __restrict__ x, unsigned short* __restrict__ x0T)
{
    const int f = blockIdx.x * 256 + threadIdx.x;   // 65536*64
    const int v = f >> 6, b = (f >> 2) & 15, c = f & 3;
    const float val = (c < 3) ? x[((size_t)b * 65536 + v) * 3 + c] : 0.0f;
    x0T[f] = __builtin_bit_cast(unsigned short, (_Float16)val);
}

// ---------- CSR builders (row-sorted edge order) ----------

__global__ __launch_bounds__(256)
void hist_edges(const int* __restrict__ r0, const int* __restrict__ r1,
                const int* __restrict__ r2, const int* __restrict__ r3,
                int* c0, int* c1, int* c2, int* c3)
{
    const int g = blockIdx.x * 256 + threadIdx.x;
    if (g < 49152)      atomicAdd(&c0[r0[g]], 1);
    else if (g < 61440) atomicAdd(&c1[r1[g - 49152]], 1);
    else if (g < 64512) atomicAdd(&c2[r2[g - 61440]], 1);
    else if (g < 65280) atomicAdd(&c3[r3[g - 64512]], 1);
}

struct ScanTasks { const int* in[4]; int* out[4]; int n[4]; };

__global__ __launch_bounds__(256)
void scan_multi(ScanTasks T)
{
    const int* in  = T.in[blockIdx.x];
    int*       out = T.out[blockIdx.x];
    const int  n   = T.n[blockIdx.x];
    __shared__ int lds[256];
    const int tid = threadIdx.x;
    const int chunk = (n + 255) / 256;
    const int base = tid * chunk;
    int s = 0;
    for (int i = 0; i < chunk; ++i) { int p = base + i; if (p < n) s += in[p]; }
    lds[tid] = s; __syncthreads();
    int acc = s;
    for (int off = 1; off < 256; off <<= 1) {
        int t = (tid >= off) ? lds[tid - off] : 0;
        __syncthreads();
        acc += t; lds[tid] = acc;
        __syncthreads();
    }
    int run = acc - s;
    for (int i = 0; i < chunk; ++i) { int p = base + i; if (p < n) { out[p] = run; run += in[p]; } }
    if (tid == 255) out[n] = run;
}

__global__ __launch_bounds__(256)
void scatter_edges(const int* __restrict__ r0, const int* __restrict__ r1,
                   const int* __restrict__ r2, const int* __restrict__ r3,
                   const int* s0, const int* s1, const int* s2, const int* s3,
                   int* u0, int* u1, int* u2, int* u3,
                   int* p0, int* p1, int* p2, int* p3)
{
    const int g = blockIdx.x * 256 + threadIdx.x;
    if (g < 49152)      { int k = g;         int r = r0[k]; p0[s0[r] + atomicAdd(&u0[r], 1)] = k; }
    else if (g < 61440) { int k = g - 49152; int r = r1[k]; p1[s1[r] + atomicAdd(&u1[r], 1)] = k; }
    else if (g < 64512) { int k = g - 61440; int r = r2[k]; p2[s2[r] + atomicAdd(&u2[r], 1)] = k; }
    else if (g < 65280) { int k = g - 64512; int r = r3[k]; p3[s3[r] + atomicAdd(&u3[r], 1)] = k; }
}

// Sorted-position tables: ce[pos]=col, rw[pos]=row, vl[pos]=val.
__global__ __launch_bounds__(256)
void build_sorted(const int* __restrict__ p0, const int* __restrict__ p1,
                  const int* __restrict__ p2, const int* __restrict__ p3,
                  const int* __restrict__ c0, const int* __restrict__ r0, const float* __restrict__ v0,
                  const int* __restrict__ c1, const int* __restrict__ r1, const float* __restrict__ v1,
                  const int* __restrict__ c2, const int* __restrict__ r2, const float* __restrict__ v2,
                  const int* __restrict__ c3, const int* __restrict__ r3, const float* __restrict__ v3,
                  int* __restrict__ CE, int* __restrict__ RW, float* __restrict__ VL)
{
    const int t = blockIdx.x * 256 + threadIdx.x;   // 65280
    if (t >= 65280) return;
    const int* perm; const int* col; const int* row; const float* val; int lp;
    if (t < 49152)      { perm = p0; col = c0; row = r0; val = v0; lp = t; }
    else if (t < 61440) { perm = p1; col = c1; row = r1; val = v1; lp = t - 49152; }
    else if (t < 64512) { perm = p2; col = c2; row = r2; val = v2; lp = t - 61440; }
    else                { perm = p3; col = c3; row = r3; val = v3; lp = t - 64512; }
    const int e = perm[lp];
    CE[t] = col[e];
    RW[t] = row[e];
    VL[t] = val[e];
}

// ---------- fused conv+ELU+pool: wave = ES edges x 16 batches ----------
// A = W^T tile (rows = couts), B = gathered fp16 x (cols = batches).
// D: row (g*4+q) = co_local, col (lane&15) = batch.
template<int CINP, int COUT, int K, int ES, int CS, int WGB, bool F16OUT>
__global__ __launch_bounds__(256)
void conv_pool_mfma(const unsigned short* __restrict__ xin, // tiled fp16
                    const int* __restrict__ idxv,    // [NV_in][9]
                    const int* __restrict__ ce,      // [nnz] sorted cols
                    const int* __restrict__ rw,      // [nnz] sorted rows
                    const float* __restrict__ vl,    // [nnz] sorted vals
                    const unsigned short* __restrict__ WTh,  // [K/32][COUT][32]
                    const unsigned short* __restrict__ WTl,
                    const float* __restrict__ bias,
                    void* __restrict__ xout_)        // zeroed
{
    constexpr int NT = COUT / 16 / CS;
    constexpr int NU = K / 32;
    constexpr int WPC = WGB / 8;
    static_assert(WGB % 8 == 0, "WGB must be divisible by 8");

    const int lane = threadIdx.x & 63, wid = threadIdx.x >> 6;
    const int b16 = lane & 15, g = lane >> 4;

    const int bid = blockIdx.x;
    const int xcd = bid & 7;
    const int r_  = bid >> 3;
    const int wgc = r_ % WPC;
    const int cs  = r_ / WPC;
    const int co0 = cs * (NT * 16);
    const int e0  = (((xcd * WPC) + wgc) * 4 + wid) * ES;

    int ce_[ES];
#pragma unroll
    for (int es = 0; es < ES; ++es) ce_[es] = ce[e0 + es];

    float4 bini[NT];
#pragma unroll
    for (int nt = 0; nt < NT; ++nt)
        bini[nt] = *(const float4*)(bias + co0 + nt * 16 + g * 4);

    f32x4 acc[ES][NT];
#pragma unroll
    for (int es = 0; es < ES; ++es)
#pragma unroll
        for (int nt = 0; nt < NT; ++nt)
            acc[es][nt] = (f32x4){bini[nt].x, bini[nt].y, bini[nt].z, bini[nt].w};

    if constexpr (CINP == 4) {
        // L0: XB0 [v][16][4]; K=64, 2 u-steps. Hoist ALL idx loads and ALL
        // 16 gathers into registers before any W-load/MFMA (max MLP).
        int vp[ES][2][2];
#pragma unroll
        for (int es = 0; es < ES; ++es)
#pragma unroll
            for (int u = 0; u < 2; ++u) {
                const int s0 = u * 8 + g * 2;
                vp[es][u][0] = (s0     < 9) ? idxv[ce_[es] * SEQL + s0]     : 0;
                vp[es][u][1] = (s0 + 1 < 9) ? idxv[ce_[es] * SEQL + s0 + 1] : 0;
            }
        f16x4 gx[ES][2][2];
#pragma unroll
        for (int es = 0; es < ES; ++es)
#pragma unroll
            for (int u = 0; u < 2; ++u) {
                gx[es][u][0] = *(const f16x4*)(xin + (size_t)vp[es][u][0] * 64 + b16 * 4);
                gx[es][u][1] = *(const f16x4*)(xin + (size_t)vp[es][u][1] * 64 + b16 * 4);
            }
#pragma unroll
        for (int u = 0; u < 2; ++u) {
            f16x8 wh[NT], wl[NT];
#pragma unroll
            for (int nt = 0; nt < NT; ++nt) {
                const size_t wo = (size_t)u * COUT * 32 + (co0 + nt * 16 + b16) * 32 + g * 8;
                wh[nt] = *(const f16x8*)(WTh + wo);
                wl[nt] = *(const f16x8*)(WTl + wo);
            }
#pragma unroll
            for (int es = 0; es < ES; ++es) {
                struct S8 { f16x4 a, b; };
                f16x8 xh = __builtin_bit_cast(f16x8, S8{gx[es][u][0], gx[es][u][1]});
#pragma unroll
                for (int nt = 0; nt < NT; ++nt) {
                    acc[es][nt] = __builtin_amdgcn_mfma_f32_16x16x32_f16(wh[nt], xh, acc[es][nt], 0, 0, 0);
                    acc[es][nt] = __builtin_amdgcn_mfma_f32_16x16x32_f16(wl[nt], xh, acc[es][nt], 0, 0, 0);
                }
            }
        }
    } else {
        constexpr int KPS = CINP / 32;
        static_assert(NU % 3 == 0, "u-loop unroll-3 needs NU % 3 == 0");
#pragma unroll 3
        for (int u = 0; u < NU; ++u) {
            const int s = u / KPS, kk = u % KPS;
            f16x8 wh[NT], wl[NT];
#pragma unroll
            for (int nt = 0; nt < NT; ++nt) {
                const size_t wo = (size_t)u * COUT * 32 + (co0 + nt * 16 + b16) * 32 + g * 8;
                wh[nt] = *(const f16x8*)(WTh + wo);
                wl[nt] = *(const f16x8*)(WTl + wo);
            }
#pragma unroll
            for (int es = 0; es < ES; ++es) {
                const int vi = idxv[ce_[es] * SEQL + s];   // wave-uniform
                const f16x8 xh = *(const f16x8*)(
                    xin + (size_t)vi * (CINP * 16) + (kk * 4 + g) * 128 + b16 * 8);
#pragma unroll
                for (int nt = 0; nt < NT; ++nt) {
                    acc[es][nt] = __builtin_amdgcn_mfma_f32_16x16x32_f16(wh[nt], xh, acc[es][nt], 0, 0, 0);
                    acc[es][nt] = __builtin_amdgcn_mfma_f32_16x16x32_f16(wl[nt], xh, acc[es][nt], 0, 0, 0);
                }
            }
        }
    }

    // Epilogue: run-merged atomics (rows sorted; wave-uniform compares).
    f32x4 mrg[NT];
#pragma unroll
    for (int nt = 0; nt < NT; ++nt) mrg[nt] = (f32x4){0.f, 0.f, 0.f, 0.f};
    int rprev = rw[e0];

    auto flush = [&](int r) {
#pragma unroll
        for (int nt = 0; nt < NT; ++nt) {
            if constexpr (F16OUT) {
                unsigned short* xout = (unsigned short*)xout_;
                const int cbase = co0 + nt * 16 + g * 4;
                unsigned short* dp = xout +
                    (((size_t)r * (COUT / 8) + (cbase >> 3)) * 16 + b16) * 8 + (cbase & 7);
                atomic_pk_f16(dp,     mrg[nt][0], mrg[nt][1]);
                atomic_pk_f16(dp + 2, mrg[nt][2], mrg[nt][3]);
            } else {
                float* xout = (float*)xout_;
#pragma unroll
                for (int q = 0; q < 4; ++q)
                    atomicAdd(xout + (size_t)r * COUT * 16 + (co0 + nt * 16 + g * 4 + q) * 16 + b16,
                              mrg[nt][q]);
            }
#pragma unroll
            for (int q = 0; q < 4; ++q) mrg[nt][q] = 0.0f;
        }
    };

#pragma unroll
    for (int es = 0; es < ES; ++es) {
        const int   r = rw[e0 + es];
        const float v = vl[e0 + es];
        if (r != rprev) { flush(rprev); rprev = r; }
#pragma unroll
        for (int nt = 0; nt < NT; ++nt)
#pragma unroll
            for (int q = 0; q < 4; ++q) {
                float y = acc[es][nt][q];
                y = (y > 0.0f) ? y : __expf(y) - 1.0f;
                mrg[nt][q] = fmaf(v, y, mrg[nt][q]);
            }
    }
    flush(rprev);
}

// ---------- final GEMM: x4 fp32 [65536 j][16 b] (j = v*256+c) ----------
__global__ __launch_bounds__(256)
void final_gemm_partial(const float* __restrict__ x4T,  // [65536][16]
                        const float* __restrict__ Wf,   // [65536][256]
                        float* __restrict__ part)       // [256][16][256]
{
    __shared__ float xs[256 * 16];
    const int j0 = blockIdx.x * 256;
    const int t  = threadIdx.x;

#pragma unroll
    for (int it = 0; it < 4; ++it) {
        const int f = t + it * 256;
        *(float4*)(xs + f * 4) = *(const float4*)(x4T + (size_t)j0 * 16 + f * 4);
    }
    __syncthreads();

    float acc[16];
#pragma unroll
    for (int b = 0; b < 16; ++b) acc[b] = 0.0f;

#pragma unroll 4
    for (int jj = 0; jj < 256; ++jj) {
        const float w = Wf[(size_t)(j0 + jj) * 256 + t];
#pragma unroll
        for (int b4 = 0; b4 < 4; ++b4) {
            const float4 xv = *(const float4*)(xs + jj * 16 + b4 * 4);
            acc[b4 * 4 + 0] = fmaf(xv.x, w, acc[b4 * 4 + 0]);
            acc[b4 * 4 + 1] = fmaf(xv.y, w, acc[b4 * 4 + 1]);
            acc[b4 * 4 + 2] = fmaf(xv.z, w, acc[b4 * 4 + 2]);
            acc[b4 * 4 + 3] = fmaf(xv.w, w, acc[b4 * 4 + 3]);
        }
    }
#pragma unroll
    for (int b = 0; b < 16; ++b)
        part[(size_t)blockIdx.x * 4096 + b * 256 + t] = acc[b];
}

__global__ __launch_bounds__(256)
void final_reduce(const float* __restrict__ part, const float* __restrict__ bf,
                  float* __restrict__ out)
{
    const int b = blockIdx.x, l = threadIdx.x;
    float s = 0.0f;
    for (int jb = 0; jb < 256; ++jb) s += part[(size_t)jb * 4096 + b * 256 + l];
    out[b * 256 + l] = s + bf[l];
}

// ---------- launch ----------
extern "C" void kernel_launch(void* const* d_in, const int* in_sizes, int n_in,
                              void* d_out, int out_size, void* d_ws, size_t ws_size,
                              hipStream_t stream)
{
    const float* x    = (const float*)d_in[0];
    const int*   idx0 = (const int*)d_in[1];
    const int*   row0 = (const int*)d_in[2];
    const int*   col0 = (const int*)d_in[3];
    const float* val0 = (const float*)d_in[4];
    const float* W0   = (const float*)d_in[5];
    const float* b0   = (const float*)d_in[6];
    const int*   idx1 = (const int*)d_in[7];
    const int*   row1 = (const int*)d_in[8];
    const int*   col1 = (const int*)d_in[9];
    const float* val1 = (const float*)d_in[10];
    const float* W1   = (const float*)d_in[11];
    const float* b1   = (const float*)d_in[12];
    const int*   idx2 = (const int*)d_in[13];
    const int*   row2 = (const int*)d_in[14];
    const int*   col2 = (const int*)d_in[15];
    const float* val2 = (const float*)d_in[16];
    const float* W2   = (const float*)d_in[17];
    const float* b2   = (const float*)d_in[18];
    const int*   idx3 = (const int*)d_in[19];
    const int*   row3 = (const int*)d_in[20];
    const int*   col3 = (const int*)d_in[21];
    const float* val3 = (const float*)d_in[22];
    const float* W3   = (const float*)d_in[23];
    const float* b3   = (const float*)d_in[24];
    const float* Wf   = (const float*)d_in[25];
    const float* bf   = (const float*)d_in[26];
    float* out = (float*)d_out;

    float* ws = (float*)d_ws;
    // fp32: x4 + part
    float* x4   = ws + 0;          // [256][256][16] = 1,048,576 f
    float* part = ws + 1048576;    // [256][16][256] = 1,048,576 f
    // fp16 tiled activations (u16 units), all disjoint:
    unsigned short* x0Tb = (unsigned short*)(ws + 2097152);   // [65536][16][4]   = 4,194,304 u16
    unsigned short* x1b  = (unsigned short*)(ws + 4194304);   // [16384][4][16][8]= 8,388,608 u16
    unsigned short* x2b  = (unsigned short*)(ws + 8388608);   // [4096][8][16][8] = 4,194,304 u16
    unsigned short* x3b  = (unsigned short*)(ws + 10485760);  // [1024][16][16][8]= 2,097,152 u16
    // Tables:
    unsigned short* wt = (unsigned short*)(ws + 12582912);
    unsigned short *WTh0 = wt,          *WTl0 = wt + 2048;
    unsigned short *WTh1 = wt + 4096,   *WTl1 = wt + 22528;
    unsigned short *WTh2 = wt + 40960,  *WTl2 = wt + 114688;
    unsigned short *WTh3 = wt + 188416, *WTl3 = wt + 483328;  // end 778240 u16
    int* CE = (int*)(ws + 12972032);   // [65280]
    int *CE0 = CE, *CE1 = CE + 49152, *CE2 = CE + 61440, *CE3 = CE + 64512;
    int* RW = (int*)(ws + 13037312);
    int *R0 = RW, *R1 = RW + 49152, *R2 = RW + 61440, *R3 = RW + 64512;
    float* VL = (ws + 13102592);
    float *V0 = VL, *V1 = VL + 49152, *V2 = VL + 61440, *V3 = VL + 64512;
    int* C = (int*)(ws + 13167872);    // CSR scratch
    int *c0 = C + 0,     *c1 = C + 16384, *c2 = C + 20480, *c3 = C + 21504;
    int *u0 = C + 21760, *u1 = C + 38144, *u2 = C + 42240, *u3 = C + 43264;
    int *s0 = C + 43520, *s1 = C + 59905, *s2 = C + 64002, *s3 = C + 65027;
    int *p0 = C + 65284, *p1 = C + 114436, *p2 = C + 126724, *p3 = C + 129796;
    // end: C + 130564 -> total ws usage ~53.2 MB

    // ---- upfront zeroing (x4 fp32 + all fp16 outputs in one span) ----
    hipMemsetAsync(x4, 0, (size_t)1048576 * 4, stream);
    hipMemsetAsync(x1b, 0, (size_t)(8388608 + 4194304 + 2097152) * 2, stream);
    hipMemsetAsync(C, 0, (size_t)43520 * sizeof(int), stream);   // c*, u*

    // ---- prep + CSR ----
    wt_prep<3,   4,   32,   64><<<   8, 256, 0, stream>>>(W0, WTh0, WTl0);
    wt_prep<32,  32,  64,  288><<<  72, 256, 0, stream>>>(W1, WTh1, WTl1);
    wt_prep<64,  64,  128, 576><<< 288, 256, 0, stream>>>(W2, WTh2, WTl2);
    wt_prep<128, 128, 256, 1152><<<1152, 256, 0, stream>>>(W3, WTh3, WTl3);
    build_x0T<<<16384, 256, 0, stream>>>(x, x0Tb);

    hist_edges<<<255, 256, 0, stream>>>(row0, row1, row2, row3, c0, c1, c2, c3);
    ScanTasks T;
    T.in[0] = c0; T.out[0] = s0; T.n[0] = 16384;
    T.in[1] = c1; T.out[1] = s1; T.n[1] = 4096;
    T.in[2] = c2; T.out[2] = s2; T.n[2] = 1024;
    T.in[3] = c3; T.out[3] = s3; T.n[3] = 256;
    scan_multi<<<4, 256, 0, stream>>>(T);
    scatter_edges<<<255, 256, 0, stream>>>(row0, row1, row2, row3,
                                           s0, s1, s2, s3, u0, u1, u2, u3,
                                           p0, p1, p2, p3);
    build_sorted<<<255, 256, 0, stream>>>(p0, p1, p2, p3,
                                          col0, row0, val0,
                                          col1, row1, val1,
                                          col2, row2, val2,
                                          col3, row3, val3,
                                          CE, RW, VL);

    // ---- L0: x0Tb -> x1b (fp16 tiled, pk atomics) ----
    conv_pool_mfma<4, 32, 64, 4, 1, 3072, true><<<3072, 256, 0, stream>>>(
        x0Tb, idx0, CE0, R0, V0, WTh0, WTl0, b0, x1b);

    // ---- L1: x1b -> x2b ----
    conv_pool_mfma<32, 64, 288, 2, 1, 1536, true><<<1536, 256, 0, stream>>>(
        x1b, idx1, CE1, R1, V1, WTh1, WTl1, b1, x2b);

    // ---- L2: x2b -> x3b ----
    conv_pool_mfma<64, 128, 576, 2, 2, 384, true><<<768, 256, 0, stream>>>(
        x2b, idx2, CE2, R2, V2, WTh2, WTl2, b2, x3b);

    // ---- L3: x3b -> x4 (fp32 atomics, feeds final GEMM) ----
    conv_pool_mfma<128, 256, 1152, 4, 8, 48, false><<<384, 256, 0, stream>>>(
        x3b, idx3, CE3, R3, V3, WTh3, WTl3, b3, x4);

    // ---- final GEMM ----
    final_gemm_partial<<<256, 256, 0, stream>>>(x4, Wf, part);
    final_reduce<<<16, 256, 0, stream>>>(part, bf, out);
}

// Round 19
// 298.497 us; speedup vs baseline: 1.0716x; 1.0716x over previous
//
#include <hip/hip_runtime.h>
#include <hip/hip_fp16.h>
#include <math.h>

// Mesh encoder: 4x (spiral conv + ELU + sparse pool) + final GEMM.
// VERTS = [65536, 16384, 4096, 1024, 256], SEQ=9, CH=[3,32,64,128,256], B=16.
//
// R12: vertex-major; wave = ES edges x 16 batches; A=W^T, B=x; sorted edges.
// R15: channel-tiled layout XB[v][c/8][b][c%8], 16B B-fragment loads.
// R17: fp16 activations + inline-asm global_atomic_pk_add_f16 direct pooling.
// R19: L1 ES 2->4 (2x gather MLP + 2x W amortization on the heaviest
// gather-demand level). Conv levels measured bound by random-gather BW
// (~1.9 TB/s effective from L2/L3 mix) — invariant at ~62us across 6
// structural variations; this is the last in-structure lever.

#define SEQL 9

typedef __attribute__((ext_vector_type(8))) _Float16 f16x8;
typedef __attribute__((ext_vector_type(4))) _Float16 f16x4;
typedef __attribute__((ext_vector_type(4))) float f32x4;

__device__ __forceinline__ void atomic_pk_f16(unsigned short* addr, float a, float b) {
    const unsigned v =
        (unsigned)__builtin_bit_cast(unsigned short, (_Float16)a) |
        ((unsigned)__builtin_bit_cast(unsigned short, (_Float16)b) << 16);
    asm volatile("global_atomic_pk_add_f16 %0, %1, off"
                 :: "v"(addr), "v"(v) : "memory");
}

// ---------- prep ----------

// W [9*CIN][COUT] fp32 -> WTh/WTl [K/32][COUT][32] fp16 hi/lo (zero-padded).
template<int CIN, int CINP, int COUT, int K>
__global__ __launch_bounds__(256)
void wt_prep(const float* __restrict__ W, unsigned short* __restrict__ WTh,
             unsigned short* __restrict__ WTl)
{
    const int t = blockIdx.x * 256 + threadIdx.x;
    if (t >= COUT * K) return;
    const int u = t / (COUT * 32);
    const int rem = t % (COUT * 32);
    const int co = rem / 32, kk = rem % 32;
    const int k = u * 32 + kk;
    const int s = k / CINP, c = k % CINP;
    float w = (s < 9 && c < CIN) ? W[(size_t)(s * CIN + c) * COUT + co] : 0.0f;
    _Float16 h = (_Float16)w;
    _Float16 l = (_Float16)(w - (float)h);
    WTh[t] = __builtin_bit_cast(unsigned short, h);
    WTl[t] = __builtin_bit_cast(unsigned short, l);
}

// x [16][65536][3] -> XB0 fp16 [65536][16][4] (c=3 zero pad)
__global__ __launch_bounds__(256)
void build_x0T(const float* __restrict__ x, unsigned short* __restrict__ x0T)
{
    const int f = blockIdx.x * 256 + threadIdx.x;   // 65536*64
    const int v = f >> 6, b = (f >> 2) & 15, c = f & 3;
    const float val = (c < 3) ? x[((size_t)b * 65536 + v) * 3 + c] : 0.0f;
    x0T[f] = __builtin_bit_cast(unsigned short, (_Float16)val);
}

// ---------- CSR builders (row-sorted edge order) ----------

__global__ __launch_bounds__(256)
void hist_edges(const int* __restrict__ r0, const int* __restrict__ r1,
                const int* __restrict__ r2, const int* __restrict__ r3,
                int* c0, int* c1, int* c2, int* c3)
{
    const int g = blockIdx.x * 256 + threadIdx.x;
    if (g < 49152)      atomicAdd(&c0[r0[g]], 1);
    else if (g < 61440) atomicAdd(&c1[r1[g - 49152]], 1);
    else if (g < 64512) atomicAdd(&c2[r2[g - 61440]], 1);
    else if (g < 65280) atomicAdd(&c3[r3[g - 64512]], 1);
}

struct ScanTasks { const int* in[4]; int* out[4]; int n[4]; };

__global__ __launch_bounds__(256)
void scan_multi(ScanTasks T)
{
    const int* in  = T.in[blockIdx.x];
    int*       out = T.out[blockIdx.x];
    const int  n   = T.n[blockIdx.x];
    __shared__ int lds[256];
    const int tid = threadIdx.x;
    const int chunk = (n + 255) / 256;
    const int base = tid * chunk;
    int s = 0;
    for (int i = 0; i < chunk; ++i) { int p = base + i; if (p < n) s += in[p]; }
    lds[tid] = s; __syncthreads();
    int acc = s;
    for (int off = 1; off < 256; off <<= 1) {
        int t = (tid >= off) ? lds[tid - off] : 0;
        __syncthreads();
        acc += t; lds[tid] = acc;
        __syncthreads();
    }
    int run = acc - s;
    for (int i = 0; i < chunk; ++i) { int p = base + i; if (p < n) { out[p] = run; run += in[p]; } }
    if (tid == 255) out[n] = run;
}

__global__ __launch_bounds__(256)
void scatter_edges(const int* __restrict__ r0, const int* __restrict__ r1,
                   const int* __restrict__ r2, const int* __restrict__ r3,
                   const int* s0, const int* s1, const int* s2, const int* s3,
                   int* u0, int* u1, int* u2, int* u3,
                   int* p0, int* p1, int* p2, int* p3)
{
    const int g = blockIdx.x * 256 + threadIdx.x;
    if (g < 49152)      { int k = g;         int r = r0[k]; p0[s0[r] + atomicAdd(&u0[r], 1)] = k; }
    else if (g < 61440) { int k = g - 49152; int r = r1[k]; p1[s1[r] + atomicAdd(&u1[r], 1)] = k; }
    else if (g < 64512) { int k = g - 61440; int r = r2[k]; p2[s2[r] + atomicAdd(&u2[r], 1)] = k; }
    else if (g < 65280) { int k = g - 64512; int r = r3[k]; p3[s3[r] + atomicAdd(&u3[r], 1)] = k; }
}

// Sorted-position tables: ce[pos]=col, rw[pos]=row, vl[pos]=val.
__global__ __launch_bounds__(256)
void build_sorted(const int* __restrict__ p0, const int* __restrict__ p1,
                  const int* __restrict__ p2, const int* __restrict__ p3,
                  const int* __restrict__ c0, const int* __restrict__ r0, const float* __restrict__ v0,
                  const int* __restrict__ c1, const int* __restrict__ r1, const float* __restrict__ v1,
                  const int* __restrict__ c2, const int* __restrict__ r2, const float* __restrict__ v2,
                  const int* __restrict__ c3, const int* __restrict__ r3, const float* __restrict__ v3,
                  int* __restrict__ CE, int* __restrict__ RW, float* __restrict__ VL)
{
    const int t = blockIdx.x * 256 + threadIdx.x;   // 65280
    if (t >= 65280) return;
    const int* perm; const int* col; const int* row; const float* val; int lp;
    if (t < 49152)      { perm = p0; col = c0; row = r0; val = v0; lp = t; }
    else if (t < 61440) { perm = p1; col = c1; row = r1; val = v1; lp = t - 49152; }
    else if (t < 64512) { perm = p2; col = c2; row = r2; val = v2; lp = t - 61440; }
    else                { perm = p3; col = c3; row = r3; val = v3; lp = t - 64512; }
    const int e = perm[lp];
    CE[t] = col[e];
    RW[t] = row[e];
    VL[t] = val[e];
}

// ---------- fused conv+ELU+pool: wave = ES edges x 16 batches ----------
// A = W^T tile (rows = couts), B = gathered fp16 x (cols = batches).
// D: row (g*4+q) = co_local, col (lane&15) = batch.
template<int CINP, int COUT, int K, int ES, int CS, int WGB, bool F16OUT>
__global__ __launch_bounds__(256)
void conv_pool_mfma(const unsigned short* __restrict__ xin, // tiled fp16
                    const int* __restrict__ idxv,    // [NV_in][9]
                    const int* __restrict__ ce,      // [nnz] sorted cols
                    const int* __restrict__ rw,      // [nnz] sorted rows
                    const float* __restrict__ vl,    // [nnz] sorted vals
                    const unsigned short* __restrict__ WTh,  // [K/32][COUT][32]
                    const unsigned short* __restrict__ WTl,
                    const float* __restrict__ bias,
                    void* __restrict__ xout_)        // zeroed
{
    constexpr int NT = COUT / 16 / CS;
    constexpr int NU = K / 32;
    constexpr int WPC = WGB / 8;
    static_assert(WGB % 8 == 0, "WGB must be divisible by 8");

    const int lane = threadIdx.x & 63, wid = threadIdx.x >> 6;
    const int b16 = lane & 15, g = lane >> 4;

    const int bid = blockIdx.x;
    const int xcd = bid & 7;
    const int r_  = bid >> 3;
    const int wgc = r_ % WPC;
    const int cs  = r_ / WPC;
    const int co0 = cs * (NT * 16);
    const int e0  = (((xcd * WPC) + wgc) * 4 + wid) * ES;

    int ce_[ES];
#pragma unroll
    for (int es = 0; es < ES; ++es) ce_[es] = ce[e0 + es];

    float4 bini[NT];
#pragma unroll
    for (int nt = 0; nt < NT; ++nt)
        bini[nt] = *(const float4*)(bias + co0 + nt * 16 + g * 4);

    f32x4 acc[ES][NT];
#pragma unroll
    for (int es = 0; es < ES; ++es)
#pragma unroll
        for (int nt = 0; nt < NT; ++nt)
            acc[es][nt] = (f32x4){bini[nt].x, bini[nt].y, bini[nt].z, bini[nt].w};

    if constexpr (CINP == 4) {
        // L0: XB0 [v][16][4]; K=64, 2 u-steps; s0 = u*8+g*2 (+1), c = j%4.
#pragma unroll
        for (int u = 0; u < 2; ++u) {
            f16x8 wh[NT], wl[NT];
#pragma unroll
            for (int nt = 0; nt < NT; ++nt) {
                const size_t wo = (size_t)u * COUT * 32 + (co0 + nt * 16 + b16) * 32 + g * 8;
                wh[nt] = *(const f16x8*)(WTh + wo);
                wl[nt] = *(const f16x8*)(WTl + wo);
            }
            const int s0 = u * 8 + g * 2;
#pragma unroll
            for (int es = 0; es < ES; ++es) {
                const int vi0 = (s0     < 9) ? idxv[ce_[es] * SEQL + s0]     : 0;
                const int vi1 = (s0 + 1 < 9) ? idxv[ce_[es] * SEQL + s0 + 1] : 0;
                const f16x4 lo = *(const f16x4*)(xin + (size_t)vi0 * 64 + b16 * 4);
                const f16x4 hi = *(const f16x4*)(xin + (size_t)vi1 * 64 + b16 * 4);
                struct S8 { f16x4 a, b; };
                f16x8 xh = __builtin_bit_cast(f16x8, S8{lo, hi});
#pragma unroll
                for (int nt = 0; nt < NT; ++nt) {
                    acc[es][nt] = __builtin_amdgcn_mfma_f32_16x16x32_f16(wh[nt], xh, acc[es][nt], 0, 0, 0);
                    acc[es][nt] = __builtin_amdgcn_mfma_f32_16x16x32_f16(wl[nt], xh, acc[es][nt], 0, 0, 0);
                }
            }
        }
    } else {
        constexpr int KPS = CINP / 32;
#pragma unroll 1
        for (int u = 0; u < NU; ++u) {
            const int s = u / KPS, kk = u % KPS;
            f16x8 wh[NT], wl[NT];
#pragma unroll
            for (int nt = 0; nt < NT; ++nt) {
                const size_t wo = (size_t)u * COUT * 32 + (co0 + nt * 16 + b16) * 32 + g * 8;
                wh[nt] = *(const f16x8*)(WTh + wo);
                wl[nt] = *(const f16x8*)(WTl + wo);
            }
#pragma unroll
            for (int es = 0; es < ES; ++es) {
                const int vi = idxv[ce_[es] * SEQL + s];   // wave-uniform
                const f16x8 xh = *(const f16x8*)(
                    xin + (size_t)vi * (CINP * 16) + (kk * 4 + g) * 128 + b16 * 8);
#pragma unroll
                for (int nt = 0; nt < NT; ++nt) {
                    acc[es][nt] = __builtin_amdgcn_mfma_f32_16x16x32_f16(wh[nt], xh, acc[es][nt], 0, 0, 0);
                    acc[es][nt] = __builtin_amdgcn_mfma_f32_16x16x32_f16(wl[nt], xh, acc[es][nt], 0, 0, 0);
                }
            }
        }
    }

    // Epilogue: run-merged atomics (rows sorted; wave-uniform compares).
    f32x4 mrg[NT];
#pragma unroll
    for (int nt = 0; nt < NT; ++nt) mrg[nt] = (f32x4){0.f, 0.f, 0.f, 0.f};
    int rprev = rw[e0];

    auto flush = [&](int r) {
#pragma unroll
        for (int nt = 0; nt < NT; ++nt) {
            if constexpr (F16OUT) {
                unsigned short* xout = (unsigned short*)xout_;
                const int cbase = co0 + nt * 16 + g * 4;
                unsigned short* dp = xout +
                    (((size_t)r * (COUT / 8) + (cbase >> 3)) * 16 + b16) * 8 + (cbase & 7);
                atomic_pk_f16(dp,     mrg[nt][0], mrg[nt][1]);
                atomic_pk_f16(dp + 2, mrg[nt][2], mrg[nt][3]);
            } else {
                float* xout = (float*)xout_;
#pragma unroll
                for (int q = 0; q < 4; ++q)
                    atomicAdd(xout + (size_t)r * COUT * 16 + (co0 + nt * 16 + g * 4 + q) * 16 + b16,
                              mrg[nt][q]);
            }
#pragma unroll
            for (int q = 0; q < 4; ++q) mrg[nt][q] = 0.0f;
        }
    };

#pragma unroll
    for (int es = 0; es < ES; ++es) {
        const int   r = rw[e0 + es];
        const float v = vl[e0 + es];
        if (r != rprev) { flush(rprev); rprev = r; }
#pragma unroll
        for (int nt = 0; nt < NT; ++nt)
#pragma unroll
            for (int q = 0; q < 4; ++q) {
                float y = acc[es][nt][q];
                y = (y > 0.0f) ? y : __expf(y) - 1.0f;
                mrg[nt][q] = fmaf(v, y, mrg[nt][q]);
            }
    }
    flush(rprev);
}

// ---------- final GEMM: x4 fp32 [65536 j][16 b] (j = v*256+c) ----------
__global__ __launch_bounds__(256)
void final_gemm_partial(const float* __restrict__ x4T,  // [65536][16]
                        const float* __restrict__ Wf,   // [65536][256]
                        float* __restrict__ part)       // [256][16][256]
{
    __shared__ float xs[256 * 16];
    const int j0 = blockIdx.x * 256;
    const int t  = threadIdx.x;

#pragma unroll
    for (int it = 0; it < 4; ++it) {
        const int f = t + it * 256;
        *(float4*)(xs + f * 4) = *(const float4*)(x4T + (size_t)j0 * 16 + f * 4);
    }
    __syncthreads();

    float acc[16];
#pragma unroll
    for (int b = 0; b < 16; ++b) acc[b] = 0.0f;

#pragma unroll 4
    for (int jj = 0; jj < 256; ++jj) {
        const float w = Wf[(size_t)(j0 + jj) * 256 + t];
#pragma unroll
        for (int b4 = 0; b4 < 4; ++b4) {
            const float4 xv = *(const float4*)(xs + jj * 16 + b4 * 4);
            acc[b4 * 4 + 0] = fmaf(xv.x, w, acc[b4 * 4 + 0]);
            acc[b4 * 4 + 1] = fmaf(xv.y, w, acc[b4 * 4 + 1]);
            acc[b4 * 4 + 2] = fmaf(xv.z, w, acc[b4 * 4 + 2]);
            acc[b4 * 4 + 3] = fmaf(xv.w, w, acc[b4 * 4 + 3]);
        }
    }
#pragma unroll
    for (int b = 0; b < 16; ++b)
        part[(size_t)blockIdx.x * 4096 + b * 256 + t] = acc[b];
}

__global__ __launch_bounds__(256)
void final_reduce(const float* __restrict__ part, const float* __restrict__ bf,
                  float* __restrict__ out)
{
    const int b = blockIdx.x, l = threadIdx.x;
    float s = 0.0f;
    for (int jb = 0; jb < 256; ++jb) s += part[(size_t)jb * 4096 + b * 256 + l];
    out[b * 256 + l] = s + bf[l];
}

// ---------- launch ----------
extern "C" void kernel_launch(void* const* d_in, const int* in_sizes, int n_in,
                              void* d_out, int out_size, void* d_ws, size_t ws_size,
                              hipStream_t stream)
{
    const float* x    = (const float*)d_in[0];
    const int*   idx0 = (const int*)d_in[1];
    const int*   row0 = (const int*)d_in[2];
    const int*   col0 = (const int*)d_in[3];
    const float* val0 = (const float*)d_in[4];
    const float* W0   = (const float*)d_in[5];
    const float* b0   = (const float*)d_in[6];
    const int*   idx1 = (const int*)d_in[7];
    const int*   row1 = (const int*)d_in[8];
    const int*   col1 = (const int*)d_in[9];
    const float* val1 = (const float*)d_in[10];
    const float* W1   = (const float*)d_in[11];
    const float* b1   = (const float*)d_in[12];
    const int*   idx2 = (const int*)d_in[13];
    const int*   row2 = (const int*)d_in[14];
    const int*   col2 = (const int*)d_in[15];
    const float* val2 = (const float*)d_in[16];
    const float* W2   = (const float*)d_in[17];
    const float* b2   = (const float*)d_in[18];
    const int*   idx3 = (const int*)d_in[19];
    const int*   row3 = (const int*)d_in[20];
    const int*   col3 = (const int*)d_in[21];
    const float* val3 = (const float*)d_in[22];
    const float* W3   = (const float*)d_in[23];
    const float* b3   = (const float*)d_in[24];
    const float* Wf   = (const float*)d_in[25];
    const float* bf   = (const float*)d_in[26];
    float* out = (float*)d_out;

    float* ws = (float*)d_ws;
    // fp32: x4 + part
    float* x4   = ws + 0;          // [256][256][16] = 1,048,576 f
    float* part = ws + 1048576;    // [256][16][256] = 1,048,576 f
    // fp16 tiled activations (u16 units), all disjoint:
    unsigned short* x0Tb = (unsigned short*)(ws + 2097152);   // [65536][16][4]   = 4,194,304 u16
    unsigned short* x1b  = (unsigned short*)(ws + 4194304);   // [16384][4][16][8]= 8,388,608 u16
    unsigned short* x2b  = (unsigned short*)(ws + 8388608);   // [4096][8][16][8] = 4,194,304 u16
    unsigned short* x3b  = (unsigned short*)(ws + 10485760);  // [1024][16][16][8]= 2,097,152 u16
    // Tables:
    unsigned short* wt = (unsigned short*)(ws + 12582912);
    unsigned short *WTh0 = wt,          *WTl0 = wt + 2048;
    unsigned short *WTh1 = wt + 4096,   *WTl1 = wt + 22528;
    unsigned short *WTh2 = wt + 40960,  *WTl2 = wt + 114688;
    unsigned short *WTh3 = wt + 188416, *WTl3 = wt + 483328;  // end 778240 u16
    int* CE = (int*)(ws + 12972032);   // [65280]
    int *CE0 = CE, *CE1 = CE + 49152, *CE2 = CE + 61440, *CE3 = CE + 64512;
    int* RW = (int*)(ws + 13037312);
    int *R0 = RW, *R1 = RW + 49152, *R2 = RW + 61440, *R3 = RW + 64512;
    float* VL = (ws + 13102592);
    float *V0 = VL, *V1 = VL + 49152, *V2 = VL + 61440, *V3 = VL + 64512;
    int* C = (int*)(ws + 13167872);    // CSR scratch
    int *c0 = C + 0,     *c1 = C + 16384, *c2 = C + 20480, *c3 = C + 21504;
    int *u0 = C + 21760, *u1 = C + 38144, *u2 = C + 42240, *u3 = C + 43264;
    int *s0 = C + 43520, *s1 = C + 59905, *s2 = C + 64002, *s3 = C + 65027;
    int *p0 = C + 65284, *p1 = C + 114436, *p2 = C + 126724, *p3 = C + 129796;
    // end: C + 130564 -> total ws usage ~53.2 MB

    // ---- prep + CSR ----
    hipMemsetAsync(C, 0, (size_t)43520 * sizeof(int), stream);   // c*, u*
    wt_prep<3,   4,   32,   64><<<   8, 256, 0, stream>>>(W0, WTh0, WTl0);
    wt_prep<32,  32,  64,  288><<<  72, 256, 0, stream>>>(W1, WTh1, WTl1);
    wt_prep<64,  64,  128, 576><<< 288, 256, 0, stream>>>(W2, WTh2, WTl2);
    wt_prep<128, 128, 256, 1152><<<1152, 256, 0, stream>>>(W3, WTh3, WTl3);
    build_x0T<<<16384, 256, 0, stream>>>(x, x0Tb);

    hist_edges<<<255, 256, 0, stream>>>(row0, row1, row2, row3, c0, c1, c2, c3);
    ScanTasks T;
    T.in[0] = c0; T.out[0] = s0; T.n[0] = 16384;
    T.in[1] = c1; T.out[1] = s1; T.n[1] = 4096;
    T.in[2] = c2; T.out[2] = s2; T.n[2] = 1024;
    T.in[3] = c3; T.out[3] = s3; T.n[3] = 256;
    scan_multi<<<4, 256, 0, stream>>>(T);
    scatter_edges<<<255, 256, 0, stream>>>(row0, row1, row2, row3,
                                           s0, s1, s2, s3, u0, u1, u2, u3,
                                           p0, p1, p2, p3);
    build_sorted<<<255, 256, 0, stream>>>(p0, p1, p2, p3,
                                          col0, row0, val0,
                                          col1, row1, val1,
                                          col2, row2, val2,
                                          col3, row3, val3,
                                          CE, RW, VL);

    // ---- L0: x0Tb -> x1b (fp16 tiled, pk atomics) ----
    hipMemsetAsync(x1b, 0, (size_t)8388608 * 2, stream);
    conv_pool_mfma<4, 32, 64, 4, 1, 3072, true><<<3072, 256, 0, stream>>>(
        x0Tb, idx0, CE0, R0, V0, WTh0, WTl0, b0, x1b);

    // ---- L1: x1b -> x2b (ES=4: 4 edges/wave, 2x gather MLP) ----
    hipMemsetAsync(x2b, 0, (size_t)4194304 * 2, stream);
    conv_pool_mfma<32, 64, 288, 4, 1, 768, true><<<768, 256, 0, stream>>>(
        x1b, idx1, CE1, R1, V1, WTh1, WTl1, b1, x2b);

    // ---- L2: x2b -> x3b ----
    hipMemsetAsync(x3b, 0, (size_t)2097152 * 2, stream);
    conv_pool_mfma<64, 128, 576, 2, 2, 384, true><<<768, 256, 0, stream>>>(
        x2b, idx2, CE2, R2, V2, WTh2, WTl2, b2, x3b);

    // ---- L3: x3b -> x4 (fp32 atomics, feeds final GEMM) ----
    hipMemsetAsync(x4, 0, (size_t)1048576 * 4, stream);
    conv_pool_mfma<128, 256, 1152, 4, 8, 48, false><<<384, 256, 0, stream>>>(
        x3b, idx3, CE3, R3, V3, WTh3, WTl3, b3, x4);

    // ---- final GEMM ----
    final_gemm_partial<<<256, 256, 0, stream>>>(x4, Wf, part);
    final_reduce<<<16, 256, 0, stream>>>(part, bf, out);
}

// Round 20
// 297.302 us; speedup vs baseline: 1.0759x; 1.0040x over previous
//
#include <hip/hip_runtime.h>
#include <hip/hip_fp16.h>
#include <math.h>

// Mesh encoder: 4x (spiral conv + ELU + sparse pool) + final GEMM.
// VERTS = [65536, 16384, 4096, 1024, 256], SEQ=9, CH=[3,32,64,128,256], B=16.
//
// R12: vertex-major; wave = ES edges x 16 batches; A=W^T, B=x; sorted edges.
// R15: channel-tiled layout XB[v][c/8][b][c%8], 16B B-fragment loads.
// R17: fp16 activations + inline-asm global_atomic_pk_add_f16 direct pooling.
// R19: L1 ES 2->4 (2x gather MLP + 2x W amortization on the heaviest
// gather-demand level). Conv levels measured bound by random-gather BW
// (~1.9 TB/s effective from L2/L3 mix) — invariant at ~62us across 6
// structural variations; this is the last in-structure lever.

#define SEQL 9

typedef __attribute__((ext_vector_type(8))) _Float16 f16x8;
typedef __attribute__((ext_vector_type(4))) _Float16 f16x4;
typedef __attribute__((ext_vector_type(4))) float f32x4;

__device__ __forceinline__ void atomic_pk_f16(unsigned short* addr, float a, float b) {
    const unsigned v =
        (unsigned)__builtin_bit_cast(unsigned short, (_Float16)a) |
        ((unsigned)__builtin_bit_cast(unsigned short, (_Float16)b) << 16);
    asm volatile("global_atomic_pk_add_f16 %0, %1, off"
                 :: "v"(addr), "v"(v) : "memory");
}

// ---------- prep ----------

// W [9*CIN][COUT] fp32 -> WTh/WTl [K/32][COUT][32] fp16 hi/lo (zero-padded).
template<int CIN, int CINP, int COUT, int K>
__global__ __launch_bounds__(256)
void wt_prep(const float* __restrict__ W, unsigned short* __restrict__ WTh,
             unsigned short* __restrict__ WTl)
{
    const int t = blockIdx.x * 256 + threadIdx.x;
    if (t >= COUT * K) return;
    const int u = t / (COUT * 32);
    const int rem = t % (COUT * 32);
    const int co = rem / 32, kk = rem % 32;
    const int k = u * 32 + kk;
    const int s = k / CINP, c = k % CINP;
    float w = (s < 9 && c < CIN) ? W[(size_t)(s * CIN + c) * COUT + co] : 0.0f;
    _Float16 h = (_Float16)w;
    _Float16 l = (_Float16)(w - (float)h);
    WTh[t] = __builtin_bit_cast(unsigned short, h);
    WTl[t] = __builtin_bit_cast(unsigned short, l);
}

// x [16][65536][3] -> XB0 fp16 [65536][16][4] (c=3 zero pad)
__global__ __launch_bounds__(256)
void build_x0T(const float* __restrict__ x, unsigned short* __restrict__ x0T)
{
    const int f = blockIdx.x * 256 + threadIdx.x;   // 65536*64
    const int v = f >> 6, b = (f >> 2) & 15, c = f & 3;
    const float val = (c < 3) ? x[((size_t)b * 65536 + v) * 3 + c] : 0.0f;
    x0T[f] = __builtin_bit_cast(unsigned short, (_Float16)val);
}

// ---------- CSR builders (row-sorted edge order) ----------

__global__ __launch_bounds__(256)
void hist_edges(const int* __restrict__ r0, const int* __restrict__ r1,
                const int* __restrict__ r2, const int* __restrict__ r3,
                int* c0, int* c1, int* c2, int* c3)
{
    const int g = blockIdx.x * 256 + threadIdx.x;
    if (g < 49152)      atomicAdd(&c0[r0[g]], 1);
    else if (g < 61440) atomicAdd(&c1[r1[g - 49152]], 1);
    else if (g < 64512) atomicAdd(&c2[r2[g - 61440]], 1);
    else if (g < 65280) atomicAdd(&c3[r3[g - 64512]], 1);
}

struct ScanTasks { const int* in[4]; int* out[4]; int n[4]; };

__global__ __launch_bounds__(256)
void scan_multi(ScanTasks T)
{
    const int* in  = T.in[blockIdx.x];
    int*       out = T.out[blockIdx.x];
    const int  n   = T.n[blockIdx.x];
    __shared__ int lds[256];
    const int tid = threadIdx.x;
    const int chunk = (n + 255) / 256;
    const int base = tid * chunk;
    int s = 0;
    for (int i = 0; i < chunk; ++i) { int p = base + i; if (p < n) s += in[p]; }
    lds[tid] = s; __syncthreads();
    int acc = s;
    for (int off = 1; off < 256; off <<= 1) {
        int t = (tid >= off) ? lds[tid - off] : 0;
        __syncthreads();
        acc += t; lds[tid] = acc;
        __syncthreads();
    }
    int run = acc - s;
    for (int i = 0; i < chunk; ++i) { int p = base + i; if (p < n) { out[p] = run; run += in[p]; } }
    if (tid == 255) out[n] = run;
}

__global__ __launch_bounds__(256)
void scatter_edges(const int* __restrict__ r0, const int* __restrict__ r1,
                   const int* __restrict__ r2, const int* __restrict__ r3,
                   const int* s0, const int* s1, const int* s2, const int* s3,
                   int* u0, int* u1, int* u2, int* u3,
                   int* p0, int* p1, int* p2, int* p3)
{
    const int g = blockIdx.x * 256 + threadIdx.x;
    if (g < 49152)      { int k = g;         int r = r0[k]; p0[s0[r] + atomicAdd(&u0[r], 1)] = k; }
    else if (g < 61440) { int k = g - 49152; int r = r1[k]; p1[s1[r] + atomicAdd(&u1[r], 1)] = k; }
    else if (g < 64512) { int k = g - 61440; int r = r2[k]; p2[s2[r] + atomicAdd(&u2[r], 1)] = k; }
    else if (g < 65280) { int k = g - 64512; int r = r3[k]; p3[s3[r] + atomicAdd(&u3[r], 1)] = k; }
}

// Sorted-position tables: ce[pos]=col, rw[pos]=row, vl[pos]=val.
__global__ __launch_bounds__(256)
void build_sorted(const int* __restrict__ p0, const int* __restrict__ p1,
                  const int* __restrict__ p2, const int* __restrict__ p3,
                  const int* __restrict__ c0, const int* __restrict__ r0, const float* __restrict__ v0,
                  const int* __restrict__ c1, const int* __restrict__ r1, const float* __restrict__ v1,
                  const int* __restrict__ c2, const int* __restrict__ r2, const float* __restrict__ v2,
                  const int* __restrict__ c3, const int* __restrict__ r3, const float* __restrict__ v3,
                  int* __restrict__ CE, int* __restrict__ RW, float* __restrict__ VL)
{
    const int t = blockIdx.x * 256 + threadIdx.x;   // 65280
    if (t >= 65280) return;
    const int* perm; const int* col; const int* row; const float* val; int lp;
    if (t < 49152)      { perm = p0; col = c0; row = r0; val = v0; lp = t; }
    else if (t < 61440) { perm = p1; col = c1; row = r1; val = v1; lp = t - 49152; }
    else if (t < 64512) { perm = p2; col = c2; row = r2; val = v2; lp = t - 61440; }
    else                { perm = p3; col = c3; row = r3; val = v3; lp = t - 64512; }
    const int e = perm[lp];
    CE[t] = col[e];
    RW[t] = row[e];
    VL[t] = val[e];
}

// ---------- fused conv+ELU+pool: wave = ES edges x 16 batches ----------
// A = W^T tile (rows = couts), B = gathered fp16 x (cols = batches).
// D: row (g*4+q) = co_local, col (lane&15) = batch.
template<int CINP, int COUT, int K, int ES, int CS, int WGB, bool F16OUT>
__global__ __launch_bounds__(256)
void conv_pool_mfma(const unsigned short* __restrict__ xin, // tiled fp16
                    const int* __restrict__ idxv,    // [NV_in][9]
                    const int* __restrict__ ce,      // [nnz] sorted cols
                    const int* __restrict__ rw,      // [nnz] sorted rows
                    const float* __restrict__ vl,    // [nnz] sorted vals
                    const unsigned short* __restrict__ WTh,  // [K/32][COUT][32]
                    const unsigned short* __restrict__ WTl,
                    const float* __restrict__ bias,
                    void* __restrict__ xout_)        // zeroed
{
    constexpr int NT = COUT / 16 / CS;
    constexpr int NU = K / 32;
    constexpr int WPC = WGB / 8;
    static_assert(WGB % 8 == 0, "WGB must be divisible by 8");

    const int lane = threadIdx.x & 63, wid = threadIdx.x >> 6;
    const int b16 = lane & 15, g = lane >> 4;

    const int bid = blockIdx.x;
    const int xcd = bid & 7;
    const int r_  = bid >> 3;
    const int wgc = r_ % WPC;
    const int cs  = r_ / WPC;
    const int co0 = cs * (NT * 16);
    const int e0  = (((xcd * WPC) + wgc) * 4 + wid) * ES;

    int ce_[ES];
#pragma unroll
    for (int es = 0; es < ES; ++es) ce_[es] = ce[e0 + es];

    float4 bini[NT];
#pragma unroll
    for (int nt = 0; nt < NT; ++nt)
        bini[nt] = *(const float4*)(bias + co0 + nt * 16 + g * 4);

    f32x4 acc[ES][NT];
#pragma unroll
    for (int es = 0; es < ES; ++es)
#pragma unroll
        for (int nt = 0; nt < NT; ++nt)
            acc[es][nt] = (f32x4){bini[nt].x, bini[nt].y, bini[nt].z, bini[nt].w};

    if constexpr (CINP == 4) {
        // L0: XB0 [v][16][4]; K=64, 2 u-steps; s0 = u*8+g*2 (+1), c = j%4.
#pragma unroll
        for (int u = 0; u < 2; ++u) {
            f16x8 wh[NT], wl[NT];
#pragma unroll
            for (int nt = 0; nt < NT; ++nt) {
                const size_t wo = (size_t)u * COUT * 32 + (co0 + nt * 16 + b16) * 32 + g * 8;
                wh[nt] = *(const f16x8*)(WTh + wo);
                wl[nt] = *(const f16x8*)(WTl + wo);
            }
            const int s0 = u * 8 + g * 2;
#pragma unroll
            for (int es = 0; es < ES; ++es) {
                const int vi0 = (s0     < 9) ? idxv[ce_[es] * SEQL + s0]     : 0;
                const int vi1 = (s0 + 1 < 9) ? idxv[ce_[es] * SEQL + s0 + 1] : 0;
                const f16x4 lo = *(const f16x4*)(xin + (size_t)vi0 * 64 + b16 * 4);
                const f16x4 hi = *(const f16x4*)(xin + (size_t)vi1 * 64 + b16 * 4);
                struct S8 { f16x4 a, b; };
                f16x8 xh = __builtin_bit_cast(f16x8, S8{lo, hi});
#pragma unroll
                for (int nt = 0; nt < NT; ++nt) {
                    acc[es][nt] = __builtin_amdgcn_mfma_f32_16x16x32_f16(wh[nt], xh, acc[es][nt], 0, 0, 0);
                    acc[es][nt] = __builtin_amdgcn_mfma_f32_16x16x32_f16(wl[nt], xh, acc[es][nt], 0, 0, 0);
                }
            }
        }
    } else {
        constexpr int KPS = CINP / 32;
#pragma unroll 1
        for (int u = 0; u < NU; ++u) {
            const int s = u / KPS, kk = u % KPS;
            f16x8 wh[NT], wl[NT];
#pragma unroll
            for (int nt = 0; nt < NT; ++nt) {
                const size_t wo = (size_t)u * COUT * 32 + (co0 + nt * 16 + b16) * 32 + g * 8;
                wh[nt] = *(const f16x8*)(WTh + wo);
                wl[nt] = *(const f16x8*)(WTl + wo);
            }
#pragma unroll
            for (int es = 0; es < ES; ++es) {
                const int vi = idxv[ce_[es] * SEQL + s];   // wave-uniform
                const f16x8 xh = *(const f16x8*)(
                    xin + (size_t)vi * (CINP * 16) + (kk * 4 + g) * 128 + b16 * 8);
#pragma unroll
                for (int nt = 0; nt < NT; ++nt) {
                    acc[es][nt] = __builtin_amdgcn_mfma_f32_16x16x32_f16(wh[nt], xh, acc[es][nt], 0, 0, 0);
                    acc[es][nt] = __builtin_amdgcn_mfma_f32_16x16x32_f16(wl[nt], xh, acc[es][nt], 0, 0, 0);
                }
            }
        }
    }

    // Epilogue: run-merged atomics (rows sorted; wave-uniform compares).
    f32x4 mrg[NT];
#pragma unroll
    for (int nt = 0; nt < NT; ++nt) mrg[nt] = (f32x4){0.f, 0.f, 0.f, 0.f};
    int rprev = rw[e0];

    auto flush = [&](int r) {
#pragma unroll
        for (int nt = 0; nt < NT; ++nt) {
            if constexpr (F16OUT) {
                unsigned short* xout = (unsigned short*)xout_;
                const int cbase = co0 + nt * 16 + g * 4;
                unsigned short* dp = xout +
                    (((size_t)r * (COUT / 8) + (cbase >> 3)) * 16 + b16) * 8 + (cbase & 7);
                atomic_pk_f16(dp,     mrg[nt][0], mrg[nt][1]);
                atomic_pk_f16(dp + 2, mrg[nt][2], mrg[nt][3]);
            } else {
                float* xout = (float*)xout_;
#pragma unroll
                for (int q = 0; q < 4; ++q)
                    atomicAdd(xout + (size_t)r * COUT * 16 + (co0 + nt * 16 + g * 4 + q) * 16 + b16,
                              mrg[nt][q]);
            }
#pragma unroll
            for (int q = 0; q < 4; ++q) mrg[nt][q] = 0.0f;
        }
    };

#pragma unroll
    for (int es = 0; es < ES; ++es) {
        const int   r = rw[e0 + es];
        const float v = vl[e0 + es];
        if (r != rprev) { flush(rprev); rprev = r; }
#pragma unroll
        for (int nt = 0; nt < NT; ++nt)
#pragma unroll
            for (int q = 0; q < 4; ++q) {
                float y = acc[es][nt][q];
                y = (y > 0.0f) ? y : __expf(y) - 1.0f;
                mrg[nt][q] = fmaf(v, y, mrg[nt][q]);
            }
    }
    flush(rprev);
}

// ---------- final GEMM: x4 fp32 [65536 j][16 b] (j = v*256+c) ----------
__global__ __launch_bounds__(256)
void final_gemm_partial(const float* __restrict__ x4T,  // [65536][16]
                        const float* __restrict__ Wf,   // [65536][256]
                        float* __restrict__ part)       // [256][16][256]
{
    __shared__ float xs[256 * 16];
    const int j0 = blockIdx.x * 256;
    const int t  = threadIdx.x;

#pragma unroll
    for (int it = 0; it < 4; ++it) {
        const int f = t + it * 256;
        *(float4*)(xs + f * 4) = *(const float4*)(x4T + (size_t)j0 * 16 + f * 4);
    }
    __syncthreads();

    float acc[16];
#pragma unroll
    for (int b = 0; b < 16; ++b) acc[b] = 0.0f;

#pragma unroll 4
    for (int jj = 0; jj < 256; ++jj) {
        const float w = Wf[(size_t)(j0 + jj) * 256 + t];
#pragma unroll
        for (int b4 = 0; b4 < 4; ++b4) {
            const float4 xv = *(const float4*)(xs + jj * 16 + b4 * 4);
            acc[b4 * 4 + 0] = fmaf(xv.x, w, acc[b4 * 4 + 0]);
            acc[b4 * 4 + 1] = fmaf(xv.y, w, acc[b4 * 4 + 1]);
            acc[b4 * 4 + 2] = fmaf(xv.z, w, acc[b4 * 4 + 2]);
            acc[b4 * 4 + 3] = fmaf(xv.w, w, acc[b4 * 4 + 3]);
        }
    }
#pragma unroll
    for (int b = 0; b < 16; ++b)
        part[(size_t)blockIdx.x * 4096 + b * 256 + t] = acc[b];
}

__global__ __launch_bounds__(256)
void final_reduce(const float* __restrict__ part, const float* __restrict__ bf,
                  float* __restrict__ out)
{
    const int b = blockIdx.x, l = threadIdx.x;
    float s = 0.0f;
    for (int jb = 0; jb < 256; ++jb) s += part[(size_t)jb * 4096 + b * 256 + l];
    out[b * 256 + l] = s + bf[l];
}

// ---------- launch ----------
extern "C" void kernel_launch(void* const* d_in, const int* in_sizes, int n_in,
                              void* d_out, int out_size, void* d_ws, size_t ws_size,
                              hipStream_t stream)
{
    const float* x    = (const float*)d_in[0];
    const int*   idx0 = (const int*)d_in[1];
    const int*   row0 = (const int*)d_in[2];
    const int*   col0 = (const int*)d_in[3];
    const float* val0 = (const float*)d_in[4];
    const float* W0   = (const float*)d_in[5];
    const float* b0   = (const float*)d_in[6];
    const int*   idx1 = (const int*)d_in[7];
    const int*   row1 = (const int*)d_in[8];
    const int*   col1 = (const int*)d_in[9];
    const float* val1 = (const float*)d_in[10];
    const float* W1   = (const float*)d_in[11];
    const float* b1   = (const float*)d_in[12];
    const int*   idx2 = (const int*)d_in[13];
    const int*   row2 = (const int*)d_in[14];
    const int*   col2 = (const int*)d_in[15];
    const float* val2 = (const float*)d_in[16];
    const float* W2   = (const float*)d_in[17];
    const float* b2   = (const float*)d_in[18];
    const int*   idx3 = (const int*)d_in[19];
    const int*   row3 = (const int*)d_in[20];
    const int*   col3 = (const int*)d_in[21];
    const float* val3 = (const float*)d_in[22];
    const float* W3   = (const float*)d_in[23];
    const float* b3   = (const float*)d_in[24];
    const float* Wf   = (const float*)d_in[25];
    const float* bf   = (const float*)d_in[26];
    float* out = (float*)d_out;

    float* ws = (float*)d_ws;
    // fp32: x4 + part
    float* x4   = ws + 0;          // [256][256][16] = 1,048,576 f
    float* part = ws + 1048576;    // [256][16][256] = 1,048,576 f
    // fp16 tiled activations (u16 units), all disjoint:
    unsigned short* x0Tb = (unsigned short*)(ws + 2097152);   // [65536][16][4]   = 4,194,304 u16
    unsigned short* x1b  = (unsigned short*)(ws + 4194304);   // [16384][4][16][8]= 8,388,608 u16
    unsigned short* x2b  = (unsigned short*)(ws + 8388608);   // [4096][8][16][8] = 4,194,304 u16
    unsigned short* x3b  = (unsigned short*)(ws + 10485760);  // [1024][16][16][8]= 2,097,152 u16
    // Tables:
    unsigned short* wt = (unsigned short*)(ws + 12582912);
    unsigned short *WTh0 = wt,          *WTl0 = wt + 2048;
    unsigned short *WTh1 = wt + 4096,   *WTl1 = wt + 22528;
    unsigned short *WTh2 = wt + 40960,  *WTl2 = wt + 114688;
    unsigned short *WTh3 = wt + 188416, *WTl3 = wt + 483328;  // end 778240 u16
    int* CE = (int*)(ws + 12972032);   // [65280]
    int *CE0 = CE, *CE1 = CE + 49152, *CE2 = CE + 61440, *CE3 = CE + 64512;
    int* RW = (int*)(ws + 13037312);
    int *R0 = RW, *R1 = RW + 49152, *R2 = RW + 61440, *R3 = RW + 64512;
    float* VL = (ws + 13102592);
    float *V0 = VL, *V1 = VL + 49152, *V2 = VL + 61440, *V3 = VL + 64512;
    int* C = (int*)(ws + 13167872);    // CSR scratch
    int *c0 = C + 0,     *c1 = C + 16384, *c2 = C + 20480, *c3 = C + 21504;
    int *u0 = C + 21760, *u1 = C + 38144, *u2 = C + 42240, *u3 = C + 43264;
    int *s0 = C + 43520, *s1 = C + 59905, *s2 = C + 64002, *s3 = C + 65027;
    int *p0 = C + 65284, *p1 = C + 114436, *p2 = C + 126724, *p3 = C + 129796;
    // end: C + 130564 -> total ws usage ~53.2 MB

    // ---- prep + CSR ----
    hipMemsetAsync(C, 0, (size_t)43520 * sizeof(int), stream);   // c*, u*
    wt_prep<3,   4,   32,   64><<<   8, 256, 0, stream>>>(W0, WTh0, WTl0);
    wt_prep<32,  32,  64,  288><<<  72, 256, 0, stream>>>(W1, WTh1, WTl1);
    wt_prep<64,  64,  128, 576><<< 288, 256, 0, stream>>>(W2, WTh2, WTl2);
    wt_prep<128, 128, 256, 1152><<<1152, 256, 0, stream>>>(W3, WTh3, WTl3);
    build_x0T<<<16384, 256, 0, stream>>>(x, x0Tb);

    hist_edges<<<255, 256, 0, stream>>>(row0, row1, row2, row3, c0, c1, c2, c3);
    ScanTasks T;
    T.in[0] = c0; T.out[0] = s0; T.n[0] = 16384;
    T.in[1] = c1; T.out[1] = s1; T.n[1] = 4096;
    T.in[2] = c2; T.out[2] = s2; T.n[2] = 1024;
    T.in[3] = c3; T.out[3] = s3; T.n[3] = 256;
    scan_multi<<<4, 256, 0, stream>>>(T);
    scatter_edges<<<255, 256, 0, stream>>>(row0, row1, row2, row3,
                                           s0, s1, s2, s3, u0, u1, u2, u3,
                                           p0, p1, p2, p3);
    build_sorted<<<255, 256, 0, stream>>>(p0, p1, p2, p3,
                                          col0, row0, val0,
                                          col1, row1, val1,
                                          col2, row2, val2,
                                          col3, row3, val3,
                                          CE, RW, VL);

    // ---- L0: x0Tb -> x1b (fp16 tiled, pk atomics) ----
    hipMemsetAsync(x1b, 0, (size_t)8388608 * 2, stream);
    conv_pool_mfma<4, 32, 64, 4, 1, 3072, true><<<3072, 256, 0, stream>>>(
        x0Tb, idx0, CE0, R0, V0, WTh0, WTl0, b0, x1b);

    // ---- L1: x1b -> x2b (ES=4: 4 edges/wave, 2x gather MLP) ----
    hipMemsetAsync(x2b, 0, (size_t)4194304 * 2, stream);
    conv_pool_mfma<32, 64, 288, 4, 1, 768, true><<<768, 256, 0, stream>>>(
        x1b, idx1, CE1, R1, V1, WTh1, WTl1, b1, x2b);

    // ---- L2: x2b -> x3b ----
    hipMemsetAsync(x3b, 0, (size_t)2097152 * 2, stream);
    conv_pool_mfma<64, 128, 576, 2, 2, 384, true><<<768, 256, 0, stream>>>(
        x2b, idx2, CE2, R2, V2, WTh2, WTl2, b2, x3b);

    // ---- L3: x3b -> x4 (fp32 atomics, feeds final GEMM) ----
    hipMemsetAsync(x4, 0, (size_t)1048576 * 4, stream);
    conv_pool_mfma<128, 256, 1152, 4, 8, 48, false><<<384, 256, 0, stream>>>(
        x3b, idx3, CE3, R3, V3, WTh3, WTl3, b3, x4);

    // ---- final GEMM ----
    final_gemm_partial<<<256, 256, 0, stream>>>(x4, Wf, part);
    final_reduce<<<16, 256, 0, stream>>>(part, bf, out);
}

// Round 21
// 285.332 us; speedup vs baseline: 1.1210x; 1.0420x over previous
//
#include <hip/hip_runtime.h>
#include <hip/hip_fp16.h>
#include <math.h>

// Mesh encoder: 4x (spiral conv + ELU + sparse pool) + final GEMM.
// VERTS = [65536, 16384, 4096, 1024, 256], SEQ=9, CH=[3,32,64,128,256], B=16.
//
// R12: vertex-major; wave = ES edges x 16 batches; A=W^T, B=x; sorted edges.
// R15: channel-tiled layout XB[v][c/8][b][c%8], 16B B-fragment loads.
// R17: fp16 activations + inline-asm global_atomic_pk_add_f16 direct pooling.
// R19: L1 ES=4 (-16us total). R20: L0 ES 4->8, L2 ES 2->4 — widening the
// per-wave edge span raises gather MLP + W amortization (proven lever).

#define SEQL 9

typedef __attribute__((ext_vector_type(8))) _Float16 f16x8;
typedef __attribute__((ext_vector_type(4))) _Float16 f16x4;
typedef __attribute__((ext_vector_type(4))) float f32x4;

__device__ __forceinline__ void atomic_pk_f16(unsigned short* addr, float a, float b) {
    const unsigned v =
        (unsigned)__builtin_bit_cast(unsigned short, (_Float16)a) |
        ((unsigned)__builtin_bit_cast(unsigned short, (_Float16)b) << 16);
    asm volatile("global_atomic_pk_add_f16 %0, %1, off"
                 :: "v"(addr), "v"(v) : "memory");
}

// ---------- prep ----------

// W [9*CIN][COUT] fp32 -> WTh/WTl [K/32][COUT][32] fp16 hi/lo (zero-padded).
template<int CIN, int CINP, int COUT, int K>
__global__ __launch_bounds__(256)
void wt_prep(const float* __restrict__ W, unsigned short* __restrict__ WTh,
             unsigned short* __restrict__ WTl)
{
    const int t = blockIdx.x * 256 + threadIdx.x;
    if (t >= COUT * K) return;
    const int u = t / (COUT * 32);
    const int rem = t % (COUT * 32);
    const int co = rem / 32, kk = rem % 32;
    const int k = u * 32 + kk;
    const int s = k / CINP, c = k % CINP;
    float w = (s < 9 && c < CIN) ? W[(size_t)(s * CIN + c) * COUT + co] : 0.0f;
    _Float16 h = (_Float16)w;
    _Float16 l = (_Float16)(w - (float)h);
    WTh[t] = __builtin_bit_cast(unsigned short, h);
    WTl[t] = __builtin_bit_cast(unsigned short, l);
}

// x [16][65536][3] -> XB0 fp16 [65536][16][4] (c=3 zero pad)
__global__ __launch_bounds__(256)
void build_x0T(const float* __restrict__ x, unsigned short* __restrict__ x0T)
{
    const int f = blockIdx.x * 256 + threadIdx.x;   // 65536*64
    const int v = f >> 6, b = (f >> 2) & 15, c = f & 3;
    const float val = (c < 3) ? x[((size_t)b * 65536 + v) * 3 + c] : 0.0f;
    x0T[f] = __builtin_bit_cast(unsigned short, (_Float16)val);
}

// ---------- CSR builders (row-sorted edge order) ----------

__global__ __launch_bounds__(256)
void hist_edges(const int* __restrict__ r0, const int* __restrict__ r1,
                const int* __restrict__ r2, const int* __restrict__ r3,
                int* c0, int* c1, int* c2, int* c3)
{
    const int g = blockIdx.x * 256 + threadIdx.x;
    if (g < 49152)      atomicAdd(&c0[r0[g]], 1);
    else if (g < 61440) atomicAdd(&c1[r1[g - 49152]], 1);
    else if (g < 64512) atomicAdd(&c2[r2[g - 61440]], 1);
    else if (g < 65280) atomicAdd(&c3[r3[g - 64512]], 1);
}

struct ScanTasks { const int* in[4]; int* out[4]; int n[4]; };

__global__ __launch_bounds__(256)
void scan_multi(ScanTasks T)
{
    const int* in  = T.in[blockIdx.x];
    int*       out = T.out[blockIdx.x];
    const int  n   = T.n[blockIdx.x];
    __shared__ int lds[256];
    const int tid = threadIdx.x;
    const int chunk = (n + 255) / 256;
    const int base = tid * chunk;
    int s = 0;
    for (int i = 0; i < chunk; ++i) { int p = base + i; if (p < n) s += in[p]; }
    lds[tid] = s; __syncthreads();
    int acc = s;
    for (int off = 1; off < 256; off <<= 1) {
        int t = (tid >= off) ? lds[tid - off] : 0;
        __syncthreads();
        acc += t; lds[tid] = acc;
        __syncthreads();
    }
    int run = acc - s;
    for (int i = 0; i < chunk; ++i) { int p = base + i; if (p < n) { out[p] = run; run += in[p]; } }
    if (tid == 255) out[n] = run;
}

__global__ __launch_bounds__(256)
void scatter_edges(const int* __restrict__ r0, const int* __restrict__ r1,
                   const int* __restrict__ r2, const int* __restrict__ r3,
                   const int* s0, const int* s1, const int* s2, const int* s3,
                   int* u0, int* u1, int* u2, int* u3,
                   int* p0, int* p1, int* p2, int* p3)
{
    const int g = blockIdx.x * 256 + threadIdx.x;
    if (g < 49152)      { int k = g;         int r = r0[k]; p0[s0[r] + atomicAdd(&u0[r], 1)] = k; }
    else if (g < 61440) { int k = g - 49152; int r = r1[k]; p1[s1[r] + atomicAdd(&u1[r], 1)] = k; }
    else if (g < 64512) { int k = g - 61440; int r = r2[k]; p2[s2[r] + atomicAdd(&u2[r], 1)] = k; }
    else if (g < 65280) { int k = g - 64512; int r = r3[k]; p3[s3[r] + atomicAdd(&u3[r], 1)] = k; }
}

// Sorted-position tables: ce[pos]=col, rw[pos]=row, vl[pos]=val.
__global__ __launch_bounds__(256)
void build_sorted(const int* __restrict__ p0, const int* __restrict__ p1,
                  const int* __restrict__ p2, const int* __restrict__ p3,
                  const int* __restrict__ c0, const int* __restrict__ r0, const float* __restrict__ v0,
                  const int* __restrict__ c1, const int* __restrict__ r1, const float* __restrict__ v1,
                  const int* __restrict__ c2, const int* __restrict__ r2, const float* __restrict__ v2,
                  const int* __restrict__ c3, const int* __restrict__ r3, const float* __restrict__ v3,
                  int* __restrict__ CE, int* __restrict__ RW, float* __restrict__ VL)
{
    const int t = blockIdx.x * 256 + threadIdx.x;   // 65280
    if (t >= 65280) return;
    const int* perm; const int* col; const int* row; const float* val; int lp;
    if (t < 49152)      { perm = p0; col = c0; row = r0; val = v0; lp = t; }
    else if (t < 61440) { perm = p1; col = c1; row = r1; val = v1; lp = t - 49152; }
    else if (t < 64512) { perm = p2; col = c2; row = r2; val = v2; lp = t - 61440; }
    else                { perm = p3; col = c3; row = r3; val = v3; lp = t - 64512; }
    const int e = perm[lp];
    CE[t] = col[e];
    RW[t] = row[e];
    VL[t] = val[e];
}

// ---------- fused conv+ELU+pool: wave = ES edges x 16 batches ----------
// A = W^T tile (rows = couts), B = gathered fp16 x (cols = batches).
// D: row (g*4+q) = co_local, col (lane&15) = batch.
template<int CINP, int COUT, int K, int ES, int CS, int WGB, bool F16OUT>
__global__ __launch_bounds__(256)
void conv_pool_mfma(const unsigned short* __restrict__ xin, // tiled fp16
                    const int* __restrict__ idxv,    // [NV_in][9]
                    const int* __restrict__ ce,      // [nnz] sorted cols
                    const int* __restrict__ rw,      // [nnz] sorted rows
                    const float* __restrict__ vl,    // [nnz] sorted vals
                    const unsigned short* __restrict__ WTh,  // [K/32][COUT][32]
                    const unsigned short* __restrict__ WTl,
                    const float* __restrict__ bias,
                    void* __restrict__ xout_)        // zeroed
{
    constexpr int NT = COUT / 16 / CS;
    constexpr int NU = K / 32;
    constexpr int WPC = WGB / 8;
    static_assert(WGB % 8 == 0, "WGB must be divisible by 8");

    const int lane = threadIdx.x & 63, wid = threadIdx.x >> 6;
    const int b16 = lane & 15, g = lane >> 4;

    const int bid = blockIdx.x;
    const int xcd = bid & 7;
    const int r_  = bid >> 3;
    const int wgc = r_ % WPC;
    const int cs  = r_ / WPC;
    const int co0 = cs * (NT * 16);
    const int e0  = (((xcd * WPC) + wgc) * 4 + wid) * ES;

    int ce_[ES];
#pragma unroll
    for (int es = 0; es < ES; ++es) ce_[es] = ce[e0 + es];

    float4 bini[NT];
#pragma unroll
    for (int nt = 0; nt < NT; ++nt)
        bini[nt] = *(const float4*)(bias + co0 + nt * 16 + g * 4);

    f32x4 acc[ES][NT];
#pragma unroll
    for (int es = 0; es < ES; ++es)
#pragma unroll
        for (int nt = 0; nt < NT; ++nt)
            acc[es][nt] = (f32x4){bini[nt].x, bini[nt].y, bini[nt].z, bini[nt].w};

    if constexpr (CINP == 4) {
        // L0: XB0 [v][16][4]; K=64, 2 u-steps; s0 = u*8+g*2 (+1), c = j%4.
#pragma unroll
        for (int u = 0; u < 2; ++u) {
            f16x8 wh[NT], wl[NT];
#pragma unroll
            for (int nt = 0; nt < NT; ++nt) {
                const size_t wo = (size_t)u * COUT * 32 + (co0 + nt * 16 + b16) * 32 + g * 8;
                wh[nt] = *(const f16x8*)(WTh + wo);
                wl[nt] = *(const f16x8*)(WTl + wo);
            }
            const int s0 = u * 8 + g * 2;
#pragma unroll
            for (int es = 0; es < ES; ++es) {
                const int vi0 = (s0     < 9) ? idxv[ce_[es] * SEQL + s0]     : 0;
                const int vi1 = (s0 + 1 < 9) ? idxv[ce_[es] * SEQL + s0 + 1] : 0;
                const f16x4 lo = *(const f16x4*)(xin + (size_t)vi0 * 64 + b16 * 4);
                const f16x4 hi = *(const f16x4*)(xin + (size_t)vi1 * 64 + b16 * 4);
                struct S8 { f16x4 a, b; };
                f16x8 xh = __builtin_bit_cast(f16x8, S8{lo, hi});
#pragma unroll
                for (int nt = 0; nt < NT; ++nt) {
                    acc[es][nt] = __builtin_amdgcn_mfma_f32_16x16x32_f16(wh[nt], xh, acc[es][nt], 0, 0, 0);
                    acc[es][nt] = __builtin_amdgcn_mfma_f32_16x16x32_f16(wl[nt], xh, acc[es][nt], 0, 0, 0);
                }
            }
        }
    } else {
        constexpr int KPS = CINP / 32;
#pragma unroll 1
        for (int u = 0; u < NU; ++u) {
            const int s = u / KPS, kk = u % KPS;
            f16x8 wh[NT], wl[NT];
#pragma unroll
            for (int nt = 0; nt < NT; ++nt) {
                const size_t wo = (size_t)u * COUT * 32 + (co0 + nt * 16 + b16) * 32 + g * 8;
                wh[nt] = *(const f16x8*)(WTh + wo);
                wl[nt] = *(const f16x8*)(WTl + wo);
            }
#pragma unroll
            for (int es = 0; es < ES; ++es) {
                const int vi = idxv[ce_[es] * SEQL + s];   // wave-uniform
                const f16x8 xh = *(const f16x8*)(
                    xin + (size_t)vi * (CINP * 16) + (kk * 4 + g) * 128 + b16 * 8);
#pragma unroll
                for (int nt = 0; nt < NT; ++nt) {
                    acc[es][nt] = __builtin_amdgcn_mfma_f32_16x16x32_f16(wh[nt], xh, acc[es][nt], 0, 0, 0);
                    acc[es][nt] = __builtin_amdgcn_mfma_f32_16x16x32_f16(wl[nt], xh, acc[es][nt], 0, 0, 0);
                }
            }
        }
    }

    // Epilogue: run-merged atomics (rows sorted; wave-uniform compares).
    f32x4 mrg[NT];
#pragma unroll
    for (int nt = 0; nt < NT; ++nt) mrg[nt] = (f32x4){0.f, 0.f, 0.f, 0.f};
    int rprev = rw[e0];

    auto flush = [&](int r) {
#pragma unroll
        for (int nt = 0; nt < NT; ++nt) {
            if constexpr (F16OUT) {
                unsigned short* xout = (unsigned short*)xout_;
                const int cbase = co0 + nt * 16 + g * 4;
                unsigned short* dp = xout +
                    (((size_t)r * (COUT / 8) + (cbase >> 3)) * 16 + b16) * 8 + (cbase & 7);
                atomic_pk_f16(dp,     mrg[nt][0], mrg[nt][1]);
                atomic_pk_f16(dp + 2, mrg[nt][2], mrg[nt][3]);
            } else {
                float* xout = (float*)xout_;
#pragma unroll
                for (int q = 0; q < 4; ++q)
                    atomicAdd(xout + (size_t)r * COUT * 16 + (co0 + nt * 16 + g * 4 + q) * 16 + b16,
                              mrg[nt][q]);
            }
#pragma unroll
            for (int q = 0; q < 4; ++q) mrg[nt][q] = 0.0f;
        }
    };

#pragma unroll
    for (int es = 0; es < ES; ++es) {
        const int   r = rw[e0 + es];
        const float v = vl[e0 + es];
        if (r != rprev) { flush(rprev); rprev = r; }
#pragma unroll
        for (int nt = 0; nt < NT; ++nt)
#pragma unroll
            for (int q = 0; q < 4; ++q) {
                float y = acc[es][nt][q];
                y = (y > 0.0f) ? y : __expf(y) - 1.0f;
                mrg[nt][q] = fmaf(v, y, mrg[nt][q]);
            }
    }
    flush(rprev);
}

// ---------- final GEMM: x4 fp32 [65536 j][16 b] (j = v*256+c) ----------
__global__ __launch_bounds__(256)
void final_gemm_partial(const float* __restrict__ x4T,  // [65536][16]
                        const float* __restrict__ Wf,   // [65536][256]
                        float* __restrict__ part)       // [256][16][256]
{
    __shared__ float xs[256 * 16];
    const int j0 = blockIdx.x * 256;
    const int t  = threadIdx.x;

#pragma unroll
    for (int it = 0; it < 4; ++it) {
        const int f = t + it * 256;
        *(float4*)(xs + f * 4) = *(const float4*)(x4T + (size_t)j0 * 16 + f * 4);
    }
    __syncthreads();

    float acc[16];
#pragma unroll
    for (int b = 0; b < 16; ++b) acc[b] = 0.0f;

#pragma unroll 4
    for (int jj = 0; jj < 256; ++jj) {
        const float w = Wf[(size_t)(j0 + jj) * 256 + t];
#pragma unroll
        for (int b4 = 0; b4 < 4; ++b4) {
            const float4 xv = *(const float4*)(xs + jj * 16 + b4 * 4);
            acc[b4 * 4 + 0] = fmaf(xv.x, w, acc[b4 * 4 + 0]);
            acc[b4 * 4 + 1] = fmaf(xv.y, w, acc[b4 * 4 + 1]);
            acc[b4 * 4 + 2] = fmaf(xv.z, w, acc[b4 * 4 + 2]);
            acc[b4 * 4 + 3] = fmaf(xv.w, w, acc[b4 * 4 + 3]);
        }
    }
#pragma unroll
    for (int b = 0; b < 16; ++b)
        part[(size_t)blockIdx.x * 4096 + b * 256 + t] = acc[b];
}

__global__ __launch_bounds__(256)
void final_reduce(const float* __restrict__ part, const float* __restrict__ bf,
                  float* __restrict__ out)
{
    const int b = blockIdx.x, l = threadIdx.x;
    float s = 0.0f;
    for (int jb = 0; jb < 256; ++jb) s += part[(size_t)jb * 4096 + b * 256 + l];
    out[b * 256 + l] = s + bf[l];
}

// ---------- launch ----------
extern "C" void kernel_launch(void* const* d_in, const int* in_sizes, int n_in,
                              void* d_out, int out_size, void* d_ws, size_t ws_size,
                              hipStream_t stream)
{
    const float* x    = (const float*)d_in[0];
    const int*   idx0 = (const int*)d_in[1];
    const int*   row0 = (const int*)d_in[2];
    const int*   col0 = (const int*)d_in[3];
    const float* val0 = (const float*)d_in[4];
    const float* W0   = (const float*)d_in[5];
    const float* b0   = (const float*)d_in[6];
    const int*   idx1 = (const int*)d_in[7];
    const int*   row1 = (const int*)d_in[8];
    const int*   col1 = (const int*)d_in[9];
    const float* val1 = (const float*)d_in[10];
    const float* W1   = (const float*)d_in[11];
    const float* b1   = (const float*)d_in[12];
    const int*   idx2 = (const int*)d_in[13];
    const int*   row2 = (const int*)d_in[14];
    const int*   col2 = (const int*)d_in[15];
    const float* val2 = (const float*)d_in[16];
    const float* W2   = (const float*)d_in[17];
    const float* b2   = (const float*)d_in[18];
    const int*   idx3 = (const int*)d_in[19];
    const int*   row3 = (const int*)d_in[20];
    const int*   col3 = (const int*)d_in[21];
    const float* val3 = (const float*)d_in[22];
    const float* W3   = (const float*)d_in[23];
    const float* b3   = (const float*)d_in[24];
    const float* Wf   = (const float*)d_in[25];
    const float* bf   = (const float*)d_in[26];
    float* out = (float*)d_out;

    float* ws = (float*)d_ws;
    // fp32: x4 + part
    float* x4   = ws + 0;          // [256][256][16] = 1,048,576 f
    float* part = ws + 1048576;    // [256][16][256] = 1,048,576 f
    // fp16 tiled activations (u16 units), all disjoint:
    unsigned short* x0Tb = (unsigned short*)(ws + 2097152);   // [65536][16][4]   = 4,194,304 u16
    unsigned short* x1b  = (unsigned short*)(ws + 4194304);   // [16384][4][16][8]= 8,388,608 u16
    unsigned short* x2b  = (unsigned short*)(ws + 8388608);   // [4096][8][16][8] = 4,194,304 u16
    unsigned short* x3b  = (unsigned short*)(ws + 10485760);  // [1024][16][16][8]= 2,097,152 u16
    // Tables:
    unsigned short* wt = (unsigned short*)(ws + 12582912);
    unsigned short *WTh0 = wt,          *WTl0 = wt + 2048;
    unsigned short *WTh1 = wt + 4096,   *WTl1 = wt + 22528;
    unsigned short *WTh2 = wt + 40960,  *WTl2 = wt + 114688;
    unsigned short *WTh3 = wt + 188416, *WTl3 = wt + 483328;  // end 778240 u16
    int* CE = (int*)(ws + 12972032);   // [65280]
    int *CE0 = CE, *CE1 = CE + 49152, *CE2 = CE + 61440, *CE3 = CE + 64512;
    int* RW = (int*)(ws + 13037312);
    int *R0 = RW, *R1 = RW + 49152, *R2 = RW + 61440, *R3 = RW + 64512;
    float* VL = (ws + 13102592);
    float *V0 = VL, *V1 = VL + 49152, *V2 = VL + 61440, *V3 = VL + 64512;
    int* C = (int*)(ws + 13167872);    // CSR scratch
    int *c0 = C + 0,     *c1 = C + 16384, *c2 = C + 20480, *c3 = C + 21504;
    int *u0 = C + 21760, *u1 = C + 38144, *u2 = C + 42240, *u3 = C + 43264;
    int *s0 = C + 43520, *s1 = C + 59905, *s2 = C + 64002, *s3 = C + 65027;
    int *p0 = C + 65284, *p1 = C + 114436, *p2 = C + 126724, *p3 = C + 129796;
    // end: C + 130564 -> total ws usage ~53.2 MB

    // ---- prep + CSR ----
    hipMemsetAsync(C, 0, (size_t)43520 * sizeof(int), stream);   // c*, u*
    wt_prep<3,   4,   32,   64><<<   8, 256, 0, stream>>>(W0, WTh0, WTl0);
    wt_prep<32,  32,  64,  288><<<  72, 256, 0, stream>>>(W1, WTh1, WTl1);
    wt_prep<64,  64,  128, 576><<< 288, 256, 0, stream>>>(W2, WTh2, WTl2);
    wt_prep<128, 128, 256, 1152><<<1152, 256, 0, stream>>>(W3, WTh3, WTl3);
    build_x0T<<<16384, 256, 0, stream>>>(x, x0Tb);

    hist_edges<<<255, 256, 0, stream>>>(row0, row1, row2, row3, c0, c1, c2, c3);
    ScanTasks T;
    T.in[0] = c0; T.out[0] = s0; T.n[0] = 16384;
    T.in[1] = c1; T.out[1] = s1; T.n[1] = 4096;
    T.in[2] = c2; T.out[2] = s2; T.n[2] = 1024;
    T.in[3] = c3; T.out[3] = s3; T.n[3] = 256;
    scan_multi<<<4, 256, 0, stream>>>(T);
    scatter_edges<<<255, 256, 0, stream>>>(row0, row1, row2, row3,
                                           s0, s1, s2, s3, u0, u1, u2, u3,
                                           p0, p1, p2, p3);
    build_sorted<<<255, 256, 0, stream>>>(p0, p1, p2, p3,
                                          col0, row0, val0,
                                          col1, row1, val1,
                                          col2, row2, val2,
                                          col3, row3, val3,
                                          CE, RW, VL);

    // ---- L0: x0Tb -> x1b (ES=8: 8 edges/wave, 16 gathers in flight) ----
    hipMemsetAsync(x1b, 0, (size_t)8388608 * 2, stream);
    conv_pool_mfma<4, 32, 64, 8, 1, 1536, true><<<1536, 256, 0, stream>>>(
        x0Tb, idx0, CE0, R0, V0, WTh0, WTl0, b0, x1b);

    // ---- L1: x1b -> x2b (ES=4) ----
    hipMemsetAsync(x2b, 0, (size_t)4194304 * 2, stream);
    conv_pool_mfma<32, 64, 288, 4, 1, 768, true><<<768, 256, 0, stream>>>(
        x1b, idx1, CE1, R1, V1, WTh1, WTl1, b1, x2b);

    // ---- L2: x2b -> x3b (ES=4) ----
    hipMemsetAsync(x3b, 0, (size_t)2097152 * 2, stream);
    conv_pool_mfma<64, 128, 576, 4, 2, 192, true><<<384, 256, 0, stream>>>(
        x2b, idx2, CE2, R2, V2, WTh2, WTl2, b2, x3b);

    // ---- L3: x3b -> x4 (fp32 atomics, feeds final GEMM) ----
    hipMemsetAsync(x4, 0, (size_t)1048576 * 4, stream);
    conv_pool_mfma<128, 256, 1152, 4, 8, 48, false><<<384, 256, 0, stream>>>(
        x3b, idx3, CE3, R3, V3, WTh3, WTl3, b3, x4);

    // ---- final GEMM ----
    final_gemm_partial<<<256, 256, 0, stream>>>(x4, Wf, part);
    final_reduce<<<16, 256, 0, stream>>>(part, bf, out);
}